// Round 1
// baseline (2167.650 us; speedup 1.0000x reference)
//
#include <hip/hip_runtime.h>

#define BB 4
#define NN 4096
#define CC 768
#define KNBR 4

constexpr float kEPS = 1e-5f;

// ---------------- K1: h = x + pos, sq[row] = sum(h^2) ----------------
__global__ __launch_bounds__(192) void k_prep(const float* __restrict__ x,
                                              const float* __restrict__ pos,
                                              float* __restrict__ h,
                                              float* __restrict__ sq) {
  int row = blockIdx.x;        // B*N rows
  int t = threadIdx.x;         // 192 threads, 768/4 float4 each row
  const float4* x4 = reinterpret_cast<const float4*>(x + (size_t)row * CC);
  const float4* p4 = reinterpret_cast<const float4*>(pos + (size_t)row * CC);
  float4* h4 = reinterpret_cast<float4*>(h + (size_t)row * CC);
  float4 a = x4[t];
  float4 b = p4[t];
  float4 v;
  v.x = a.x + b.x; v.y = a.y + b.y; v.z = a.z + b.z; v.w = a.w + b.w;
  h4[t] = v;
  float s = v.x * v.x + v.y * v.y + v.z * v.z + v.w * v.w;
  for (int off = 32; off > 0; off >>= 1) s += __shfl_down(s, off, 64);
  __shared__ float red[3];
  if ((t & 63) == 0) red[t >> 6] = s;
  __syncthreads();
  if (t == 0) sq[row] = red[0] + red[1] + red[2];
}

// ---------------- K2: fused Gram matrix + running top-4 ----------------
// block tile: 64 rows (n) x full m loop in tiles of 256; K-chunks of 32.
// 256 threads, each owns an 8x8 register tile.
#define DN 64
#define DM 256
#define KC 32
// smem floats: As[32][68]=2176, Bs[32][260]=8320 (staging, total 10496)
// dtile[64][129]=8256 aliases staging; sqs[256] after.
__global__ __launch_bounds__(256) void k_dist_topk(const float* __restrict__ h,
                                                   const float* __restrict__ sq,
                                                   int* __restrict__ idx) {
  __shared__ float smem[10496 + 256];
  float* As = smem;              // [KC][68]
  float* Bs = smem + KC * 68;    // [KC][260]
  float* dtile = smem;           // [64][129] (alias, used after staging dead)
  float* sqs = smem + 10496;     // [256]

  int bid = blockIdx.x;
  int b = bid >> 6;                 // 64 row-blocks per batch
  int n0 = (bid & 63) * DN;
  const float* hb = h + (size_t)b * NN * CC;
  const float* sqb = sq + (size_t)b * NN;
  int t = threadIdx.x;
  int tn = t & 7;    // row group: rows tn*8 .. tn*8+7
  int tm = t >> 3;   // col group: cols tm*8 .. tm*8+7 (0..31 -> 256)

  float best0 = -1e30f, best1 = -1e30f, best2 = -1e30f, best3 = -1e30f;
  int bi0 = 0, bi1 = 0, bi2 = 0, bi3 = 0;

  for (int m0 = 0; m0 < NN; m0 += DM) {
    __syncthreads();               // previous m-tile's dtile scan complete
    sqs[t] = sqb[m0 + t];
    float acc[8][8];
#pragma unroll
    for (int i = 0; i < 8; i++)
#pragma unroll
      for (int j = 0; j < 8; j++) acc[i][j] = 0.f;

    for (int k0 = 0; k0 < CC; k0 += KC) {
      __syncthreads();
      {
        int r = t >> 3;      // 0..31
        int cg = t & 7;      // k-group (4 floats)
#pragma unroll
        for (int p = 0; p < 2; p++) {
          int n = r + p * 32;
          float4 v = *reinterpret_cast<const float4*>(
              &hb[(size_t)(n0 + n) * CC + k0 + cg * 4]);
          As[(cg * 4 + 0) * 68 + n] = v.x;
          As[(cg * 4 + 1) * 68 + n] = v.y;
          As[(cg * 4 + 2) * 68 + n] = v.z;
          As[(cg * 4 + 3) * 68 + n] = v.w;
        }
#pragma unroll
        for (int p = 0; p < 8; p++) {
          int m = r + p * 32;
          float4 v = *reinterpret_cast<const float4*>(
              &hb[(size_t)(m0 + m) * CC + k0 + cg * 4]);
          Bs[(cg * 4 + 0) * 260 + m] = v.x;
          Bs[(cg * 4 + 1) * 260 + m] = v.y;
          Bs[(cg * 4 + 2) * 260 + m] = v.z;
          Bs[(cg * 4 + 3) * 260 + m] = v.w;
        }
      }
      __syncthreads();
      for (int k = 0; k < KC; k++) {
        float4 a0 = *reinterpret_cast<const float4*>(&As[k * 68 + tn * 8]);
        float4 a1 = *reinterpret_cast<const float4*>(&As[k * 68 + tn * 8 + 4]);
        float4 b0 = *reinterpret_cast<const float4*>(&Bs[k * 260 + tm * 8]);
        float4 b1 = *reinterpret_cast<const float4*>(&Bs[k * 260 + tm * 8 + 4]);
        float av[8] = {a0.x, a0.y, a0.z, a0.w, a1.x, a1.y, a1.z, a1.w};
        float bv[8] = {b0.x, b0.y, b0.z, b0.w, b1.x, b1.y, b1.z, b1.w};
#pragma unroll
        for (int i = 0; i < 8; i++)
#pragma unroll
          for (int j = 0; j < 8; j++)
            acc[i][j] = fmaf(av[i], bv[j], acc[i][j]);
      }
    }

    // top-4 update in two halves of 128 cols (dtile = 64x129, 2-way-free banks)
#pragma unroll
    for (int half = 0; half < 2; half++) {
      __syncthreads();   // staging reads (or prev half scan) complete
      if ((tm >> 4) == half) {
        int cm = (tm & 15) * 8;
#pragma unroll
        for (int i = 0; i < 8; i++)
#pragma unroll
          for (int j = 0; j < 8; j++)
            dtile[(tn * 8 + i) * 129 + cm + j] =
                2.f * acc[i][j] - sqs[tm * 8 + j];
      }
      __syncthreads();
      if (t < DN) {
        int mbase = m0 + half * 128;
        for (int j = 0; j < 128; j++) {
          float v = dtile[t * 129 + j];
          if (v > best3) {
            int m = mbase + j;
            best3 = v; bi3 = m;
            if (best3 > best2) { float tv = best2; best2 = best3; best3 = tv;
                                 int ti = bi2; bi2 = bi3; bi3 = ti; }
            if (best2 > best1) { float tv = best1; best1 = best2; best2 = tv;
                                 int ti = bi1; bi1 = bi2; bi2 = ti; }
            if (best1 > best0) { float tv = best0; best0 = best1; best1 = tv;
                                 int ti = bi0; bi0 = bi1; bi1 = ti; }
          }
        }
      }
    }
  }
  if (t < DN) {
    int* o = idx + ((size_t)b * NN + n0 + t) * KNBR;
    o[0] = bi0; o[1] = bi1; o[2] = bi2; o[3] = bi3;
  }
}

// ---------------- K3/K5: generic 128x128 fp32 tiled GEMM ----------------
// MODE 0: W=w1 (256x1536). B[o][c] = o<256 ? w1[o][c] : w1[o-256][768+c]-w1[o-256][c].
//         out = raw (T, 16384x512).
// MODE 1: W=w2 (768x256). B[o][c] = w2[o][c]; epilogue bn2 + leaky relu.
template <int MODE>
__global__ __launch_bounds__(256) void k_gemm(const float* __restrict__ A,
                                              const float* __restrict__ W,
                                              float* __restrict__ out,
                                              const float* __restrict__ gamma,
                                              const float* __restrict__ beta,
                                              const float* __restrict__ mean,
                                              const float* __restrict__ var,
                                              int M, int Nc, int Kd) {
  __shared__ float As[KC][132];
  __shared__ float Bs[KC][132];
  int o0 = blockIdx.x * 128;
  int m0 = blockIdx.y * 128;
  int t = threadIdx.x;
  int tn = t & 15;   // rows tn*8..
  int tm = t >> 4;   // cols tm*8..
  float acc[8][8];
#pragma unroll
  for (int i = 0; i < 8; i++)
#pragma unroll
    for (int j = 0; j < 8; j++) acc[i][j] = 0.f;

  for (int k0 = 0; k0 < Kd; k0 += KC) {
    __syncthreads();
    int r = t >> 3, cg = t & 7;
#pragma unroll
    for (int p = 0; p < 4; p++) {
      int row = r + p * 32;
      float4 v = *reinterpret_cast<const float4*>(
          &A[(size_t)(m0 + row) * Kd + k0 + cg * 4]);
      As[cg * 4 + 0][row] = v.x;
      As[cg * 4 + 1][row] = v.y;
      As[cg * 4 + 2][row] = v.z;
      As[cg * 4 + 3][row] = v.w;
    }
#pragma unroll
    for (int p = 0; p < 4; p++) {
      int o = o0 + r + p * 32;
      float4 v;
      if (MODE == 0) {
        if (o < 256) {
          v = *reinterpret_cast<const float4*>(&W[(size_t)o * 1536 + k0 + cg * 4]);
        } else {
          float4 u = *reinterpret_cast<const float4*>(
              &W[(size_t)(o - 256) * 1536 + 768 + k0 + cg * 4]);
          float4 w = *reinterpret_cast<const float4*>(
              &W[(size_t)(o - 256) * 1536 + k0 + cg * 4]);
          v.x = u.x - w.x; v.y = u.y - w.y; v.z = u.z - w.z; v.w = u.w - w.w;
        }
      } else {
        v = *reinterpret_cast<const float4*>(&W[(size_t)o * Kd + k0 + cg * 4]);
      }
      Bs[cg * 4 + 0][r + p * 32] = v.x;
      Bs[cg * 4 + 1][r + p * 32] = v.y;
      Bs[cg * 4 + 2][r + p * 32] = v.z;
      Bs[cg * 4 + 3][r + p * 32] = v.w;
    }
    __syncthreads();
    for (int k = 0; k < KC; k++) {
      float4 a0 = *reinterpret_cast<const float4*>(&As[k][tn * 8]);
      float4 a1 = *reinterpret_cast<const float4*>(&As[k][tn * 8 + 4]);
      float4 b0 = *reinterpret_cast<const float4*>(&Bs[k][tm * 8]);
      float4 b1 = *reinterpret_cast<const float4*>(&Bs[k][tm * 8 + 4]);
      float av[8] = {a0.x, a0.y, a0.z, a0.w, a1.x, a1.y, a1.z, a1.w};
      float bv[8] = {b0.x, b0.y, b0.z, b0.w, b1.x, b1.y, b1.z, b1.w};
#pragma unroll
      for (int i = 0; i < 8; i++)
#pragma unroll
        for (int j = 0; j < 8; j++)
          acc[i][j] = fmaf(av[i], bv[j], acc[i][j]);
    }
  }
#pragma unroll
  for (int i = 0; i < 8; i++) {
    int row = m0 + tn * 8 + i;
#pragma unroll
    for (int j = 0; j < 8; j++) {
      int o = o0 + tm * 8 + j;
      float v = acc[i][j];
      if (MODE == 1) {
        float s = gamma[o] * rsqrtf(var[o] + kEPS);
        v = v * s + (beta[o] - mean[o] * s);
        v = v < 0.f ? 0.2f * v : v;
      }
      out[(size_t)row * Nc + o] = v;
    }
  }
}

// ---------------- K4: gather neighbors + BN1 + LReLU + max over K ----------------
__global__ __launch_bounds__(256) void k_pool(const float* __restrict__ T,
                                              const int* __restrict__ idx,
                                              const float* __restrict__ g1,
                                              const float* __restrict__ b1,
                                              const float* __restrict__ m1,
                                              const float* __restrict__ v1,
                                              float* __restrict__ pooled) {
  int bn = blockIdx.x;
  int b = bn >> 12;     // N = 4096
  int o = threadIdx.x;  // 256 channels
  float s = g1[o] * rsqrtf(v1[o] + kEPS);
  float sh = b1[o] - m1[o] * s;
  float P = T[(size_t)bn * 512 + 256 + o];
  const int* ix = idx + (size_t)bn * KNBR;
  float mx = -1e30f;
#pragma unroll
  for (int k = 0; k < KNBR; k++) {
    int m = ix[k];
    float gg = T[((size_t)b * NN + m) * 512 + o];
    float y = (gg + P) * s + sh;
    y = y < 0.f ? 0.2f * y : y;
    mx = fmaxf(mx, y);
  }
  pooled[(size_t)bn * 256 + o] = mx;
}

extern "C" void kernel_launch(void* const* d_in, const int* in_sizes, int n_in,
                              void* d_out, int out_size, void* d_ws,
                              size_t ws_size, hipStream_t stream) {
  const float* x = (const float*)d_in[0];
  const float* pos = (const float*)d_in[1];
  const float* w1 = (const float*)d_in[2];
  const float* gamma1 = (const float*)d_in[3];
  const float* beta1 = (const float*)d_in[4];
  const float* mean1 = (const float*)d_in[5];
  const float* var1 = (const float*)d_in[6];
  const float* w2 = (const float*)d_in[7];
  const float* gamma2 = (const float*)d_in[8];
  const float* beta2 = (const float*)d_in[9];
  const float* mean2 = (const float*)d_in[10];
  const float* var2 = (const float*)d_in[11];
  float* out = (float*)d_out;

  // ws layout (floats): h[B*N*C] | sq[B*N] | idx[B*N*4] (int) | T[B*N*512] | pooled[B*N*256]
  float* ws = (float*)d_ws;
  float* h = ws;
  float* sqv = h + (size_t)BB * NN * CC;
  int* idx = (int*)(sqv + (size_t)BB * NN);
  float* T = (float*)(idx + (size_t)BB * NN * KNBR);
  float* pooled = T + (size_t)BB * NN * 512;

  k_prep<<<BB * NN, 192, 0, stream>>>(x, pos, h, sqv);
  k_dist_topk<<<BB * (NN / DN), 256, 0, stream>>>(h, sqv, idx);
  k_gemm<0><<<dim3(512 / 128, (BB * NN) / 128), 256, 0, stream>>>(
      h, w1, T, nullptr, nullptr, nullptr, nullptr, BB * NN, 512, CC);
  k_pool<<<BB * NN, 256, 0, stream>>>(T, idx, gamma1, beta1, mean1, var1, pooled);
  k_gemm<1><<<dim3(768 / 128, (BB * NN) / 128), 256, 0, stream>>>(
      pooled, w2, out, gamma2, beta2, mean2, var2, BB * NN, CC, 256);
}

// Round 2
// 500.910 us; speedup vs baseline: 4.3274x; 4.3274x over previous
//
#include <hip/hip_runtime.h>

#define BB 4
#define NN 4096
#define CC 768
#define KNBR 4
constexpr float kEPS = 1e-5f;

typedef __attribute__((ext_vector_type(8))) short short8;
typedef __attribute__((ext_vector_type(4))) float f32x4;

__device__ __forceinline__ unsigned short f2b(float f) {  // fp32 -> bf16 RNE
  unsigned u = __float_as_uint(f);
  return (unsigned short)((u + 0x7fffu + ((u >> 16) & 1u)) >> 16);
}
__device__ __forceinline__ void gld16(const void* g, void* l) {
  __builtin_amdgcn_global_load_lds(
      (const __attribute__((address_space(1))) unsigned int*)g,
      (__attribute__((address_space(3))) unsigned int*)l, 16, 0, 0);
}

// ---------------- K1: hb = bf16(x + pos), sq[row] = sum(h^2) (fp32) --------
__global__ __launch_bounds__(192) void k_prep(const float* __restrict__ x,
                                              const float* __restrict__ pos,
                                              unsigned short* __restrict__ hb,
                                              float* __restrict__ sq) {
  int row = blockIdx.x;
  int t = threadIdx.x;
  const float4* x4 = reinterpret_cast<const float4*>(x + (size_t)row * CC);
  const float4* p4 = reinterpret_cast<const float4*>(pos + (size_t)row * CC);
  float4 a = x4[t], b = p4[t];
  float4 v;
  v.x = a.x + b.x; v.y = a.y + b.y; v.z = a.z + b.z; v.w = a.w + b.w;
  unsigned lo = (unsigned)f2b(v.x) | ((unsigned)f2b(v.y) << 16);
  unsigned hi = (unsigned)f2b(v.z) | ((unsigned)f2b(v.w) << 16);
  uint2 u; u.x = lo; u.y = hi;
  *reinterpret_cast<uint2*>(hb + (size_t)row * CC + t * 4) = u;
  float s = v.x * v.x + v.y * v.y + v.z * v.z + v.w * v.w;
  for (int off = 32; off > 0; off >>= 1) s += __shfl_down(s, off, 64);
  __shared__ float red[3];
  if ((t & 63) == 0) red[t >> 6] = s;
  __syncthreads();
  if (t == 0) sq[row] = red[0] + red[1] + red[2];
}

// ---------------- K2: weight prep: W1' (512x768 bf16), W2 bf16, BN2 affine --
__global__ __launch_bounds__(256) void k_wprep(const float* __restrict__ w1,
                                               const float* __restrict__ w2,
                                               const float* __restrict__ g2,
                                               const float* __restrict__ be2,
                                               const float* __restrict__ me2,
                                               const float* __restrict__ va2,
                                               unsigned short* __restrict__ w1b,
                                               unsigned short* __restrict__ w2b,
                                               float* __restrict__ s2,
                                               float* __restrict__ sh2) {
  int t = blockIdx.x * 256 + threadIdx.x;
  if (t < 512 * 768) {
    int o = t / 768, c = t % 768;
    float val = (o < 256) ? w1[(size_t)o * 1536 + c]
                          : (w1[(size_t)(o - 256) * 1536 + 768 + c] -
                             w1[(size_t)(o - 256) * 1536 + c]);
    w1b[t] = f2b(val);
  } else if (t < 512 * 768 + 768 * 256) {
    int u = t - 512 * 768;
    w2b[u] = f2b(w2[u]);
  } else if (t < 512 * 768 + 768 * 256 + 768) {
    int c = t - (512 * 768 + 768 * 256);
    float s = g2[c] * rsqrtf(va2[c] + kEPS);
    s2[c] = s;
    sh2[c] = be2[c] - me2[c] * s;
  }
}

// ---------------- K3: bf16 MFMA GEMM template ------------------------------
// OUT[i][j] = sum_k P[i][k] * Q[j][k].  P:[M][K] bf16, Q:[N][K] bf16, ld=N.
// mfma(a=Q-frag, b=P-frag): C row-dim = j (reg-consecutive), col = i.
// MODE 0: d-tile epilogue: bf16( 2*acc - sq[j] + 768 )  (e0 = sq)
// MODE 1: raw fp32 out
// MODE 2: BN2 + leaky-relu fp32 out (e0 = s2, e1 = sh2)
template <int MODE>
__global__ __launch_bounds__(256) void k_mm(const unsigned short* __restrict__ P,
                                            const unsigned short* __restrict__ Q,
                                            void* __restrict__ outp,
                                            const float* __restrict__ e0,
                                            const float* __restrict__ e1,
                                            int K, int N, int jtiles) {
  __shared__ unsigned short lds[16384];  // Qs [0..8191], Ps [8192..16383]
  const int tid = threadIdx.x, lane = tid & 63, w = tid >> 6;
  const int wi = w >> 1, wj = w & 1;
  int nwg = gridDim.x, bid = blockIdx.x;
  int wg = (bid & 7) * (nwg >> 3) + (bid >> 3);  // XCD swizzle (nwg%8==0)
  int it = wg / jtiles, jt = wg % jtiles;
  const size_t i0 = (size_t)it * 128, j0 = (size_t)jt * 128;

  const int srow = lane >> 3;   // row-in-8 (== row&7 for all passes)
  const int chp = lane & 7;     // physical 16B chunk
  const int lc = chp ^ srow;    // logical chunk (XOR swizzle, both sides)

  f32x4 acc[4][4];
#pragma unroll
  for (int fi = 0; fi < 4; ++fi)
#pragma unroll
    for (int fj = 0; fj < 4; ++fj) acc[fi][fj] = (f32x4){0.f, 0.f, 0.f, 0.f};

  for (int k0 = 0; k0 < K; k0 += 64) {
    __syncthreads();
#pragma unroll
    for (int p = 0; p < 4; ++p) {
      int row = p * 32 + w * 8 + srow;
      gld16(Q + ((size_t)(j0 + row) * K + k0 + lc * 8), &lds[row * 64 + chp * 8]);
    }
#pragma unroll
    for (int p = 0; p < 4; ++p) {
      int row = p * 32 + w * 8 + srow;
      gld16(P + ((size_t)(i0 + row) * K + k0 + lc * 8),
            &lds[8192 + row * 64 + chp * 8]);
    }
    __syncthreads();
#pragma unroll
    for (int ks = 0; ks < 2; ++ks) {
      short8 qf[4], pf[4];
#pragma unroll
      for (int f = 0; f < 4; ++f) {
        int rq = wj * 64 + f * 16 + (lane & 15);
        int cq = (ks * 4 + (lane >> 4)) ^ (rq & 7);
        qf[f] = *(const short8*)&lds[rq * 64 + cq * 8];
        int rp = wi * 64 + f * 16 + (lane & 15);
        int cp = (ks * 4 + (lane >> 4)) ^ (rp & 7);
        pf[f] = *(const short8*)&lds[8192 + rp * 64 + cp * 8];
      }
#pragma unroll
      for (int fi = 0; fi < 4; ++fi)
#pragma unroll
        for (int fj = 0; fj < 4; ++fj)
          acc[fi][fj] = __builtin_amdgcn_mfma_f32_16x16x32_bf16(
              qf[fj], pf[fi], acc[fi][fj], 0, 0, 0);
    }
  }

#pragma unroll
  for (int fi = 0; fi < 4; ++fi) {
    size_t ig = i0 + wi * 64 + fi * 16 + (lane & 15);
#pragma unroll
    for (int fj = 0; fj < 4; ++fj) {
      size_t jg = j0 + wj * 64 + fj * 16 + ((lane >> 4) << 2);
      if (MODE == 0) {
        unsigned lo, hi;
        float v0 = 2.f * acc[fi][fj][0] - e0[jg + 0] + 768.f;
        float v1 = 2.f * acc[fi][fj][1] - e0[jg + 1] + 768.f;
        float v2 = 2.f * acc[fi][fj][2] - e0[jg + 2] + 768.f;
        float v3 = 2.f * acc[fi][fj][3] - e0[jg + 3] + 768.f;
        lo = (unsigned)f2b(v0) | ((unsigned)f2b(v1) << 16);
        hi = (unsigned)f2b(v2) | ((unsigned)f2b(v3) << 16);
        uint2 u; u.x = lo; u.y = hi;
        *(uint2*)((unsigned short*)outp + ig * (size_t)N + jg) = u;
      } else if (MODE == 1) {
        *(f32x4*)((float*)outp + ig * (size_t)N + jg) = acc[fi][fj];
      } else {
        f32x4 o4;
#pragma unroll
        for (int r = 0; r < 4; ++r) {
          size_t j = jg + r;
          float vv = acc[fi][fj][r] * e0[j] + e1[j];
          o4[r] = vv < 0.f ? 0.2f * vv : vv;
        }
        *(f32x4*)((float*)outp + ig * (size_t)N + jg) = o4;
      }
    }
  }
}

// ---------------- K4: per-row top-16 candidates + exact fp32 rescue --------
__global__ __launch_bounds__(256) void k_topk(const unsigned short* __restrict__ dt,
                                              const float* __restrict__ xb,
                                              const float* __restrict__ pb,
                                              const float* __restrict__ sqb,
                                              int* __restrict__ idxb) {
  const int w = threadIdx.x >> 6, lane = threadIdx.x & 63;
  const int n = blockIdx.x * 4 + w;

  float v[8]; int mi[8];
#pragma unroll
  for (int t = 0; t < 8; ++t) { v[t] = -3.0e38f; mi[t] = 0x7fffffff; }

  auto ins8 = [&](float val, int m) {
    if (val > v[7] || (val == v[7] && m < mi[7])) {
      v[7] = val; mi[7] = m;
#pragma unroll
      for (int t = 7; t > 0; --t)
        if (v[t] > v[t - 1] || (v[t] == v[t - 1] && mi[t] < mi[t - 1])) {
          float tv = v[t]; v[t] = v[t - 1]; v[t - 1] = tv;
          int tm = mi[t]; mi[t] = mi[t - 1]; mi[t - 1] = tm;
        }
    }
  };

  const uint4* drow = (const uint4*)(dt + (size_t)n * NN);
#pragma unroll
  for (int j = 0; j < 8; ++j) {
    uint4 q = drow[j * 64 + lane];
    int mbase = (j * 64 + lane) * 8;
    unsigned qa[4] = {q.x, q.y, q.z, q.w};
#pragma unroll
    for (int t = 0; t < 4; ++t) {
      float fl = __uint_as_float(qa[t] << 16);
      float fh = __uint_as_float(qa[t] & 0xffff0000u);
      ins8(fl, mbase + t * 2);
      ins8(fh, mbase + t * 2 + 1);
    }
  }

  // 16 rounds of wave argmax-extract (all lanes learn winner; winner pops).
  int cands[16];
#pragma unroll
  for (int r = 0; r < 16; ++r) {
    float bv = v[0]; int bm = mi[0];
#pragma unroll
    for (int off = 1; off < 64; off <<= 1) {
      float ov = __shfl_xor(bv, off, 64);
      int om = __shfl_xor(bm, off, 64);
      if (ov > bv || (ov == bv && om < bm)) { bv = ov; bm = om; }
    }
    cands[r] = bm;
    if (bm == mi[0]) {
#pragma unroll
      for (int t = 0; t < 7; ++t) { v[t] = v[t + 1]; mi[t] = mi[t + 1]; }
      v[7] = -3.0e38f; mi[7] = 0x7fffffff;
    }
  }

  // Exact fp32 rescue: h = x + pos recomputed; 16 candidate dots; top-4.
  float hn[12];
  {
    const float4* xa = (const float4*)(xb + (size_t)n * CC + lane * 12);
    const float4* pa = (const float4*)(pb + (size_t)n * CC + lane * 12);
#pragma unroll
    for (int t = 0; t < 3; ++t) {
      float4 a = xa[t], b = pa[t];
      hn[t * 4 + 0] = a.x + b.x; hn[t * 4 + 1] = a.y + b.y;
      hn[t * 4 + 2] = a.z + b.z; hn[t * 4 + 3] = a.w + b.w;
    }
  }
  float sqn = sqb[n];
  float b4v[4]; int b4m[4];
#pragma unroll
  for (int t = 0; t < 4; ++t) { b4v[t] = -3.0e38f; b4m[t] = 0x7fffffff; }

#pragma unroll
  for (int c = 0; c < 16; ++c) {
    int m = cands[c];
    const float4* xm = (const float4*)(xb + (size_t)m * CC + lane * 12);
    const float4* pm = (const float4*)(pb + (size_t)m * CC + lane * 12);
    float d = 0.f;
#pragma unroll
    for (int t = 0; t < 3; ++t) {
      float4 a = xm[t], b = pm[t];
      d = fmaf(hn[t * 4 + 0], a.x + b.x, d);
      d = fmaf(hn[t * 4 + 1], a.y + b.y, d);
      d = fmaf(hn[t * 4 + 2], a.z + b.z, d);
      d = fmaf(hn[t * 4 + 3], a.w + b.w, d);
    }
#pragma unroll
    for (int off = 1; off < 64; off <<= 1) d += __shfl_xor(d, off, 64);
    float val = (2.f * d - sqn) - sqb[m];
    if (val > b4v[3] || (val == b4v[3] && m < b4m[3])) {
      b4v[3] = val; b4m[3] = m;
#pragma unroll
      for (int t = 3; t > 0; --t)
        if (b4v[t] > b4v[t - 1] || (b4v[t] == b4v[t - 1] && b4m[t] < b4m[t - 1])) {
          float tv = b4v[t]; b4v[t] = b4v[t - 1]; b4v[t - 1] = tv;
          int tm = b4m[t]; b4m[t] = b4m[t - 1]; b4m[t - 1] = tm;
        }
    }
  }
  if (lane == 0) {
    int4 o; o.x = b4m[0]; o.y = b4m[1]; o.z = b4m[2]; o.w = b4m[3];
    *(int4*)(idxb + (size_t)n * KNBR) = o;
  }
}

// ---------------- K5: gather + BN1 + LReLU + max over K --------------------
__global__ __launch_bounds__(256) void k_pool(const float* __restrict__ T,
                                              const int* __restrict__ idx,
                                              const float* __restrict__ g1,
                                              const float* __restrict__ b1,
                                              const float* __restrict__ m1,
                                              const float* __restrict__ v1,
                                              unsigned short* __restrict__ pooledb) {
  int bn = blockIdx.x;
  int b = bn >> 12;
  int o = threadIdx.x;
  float s = g1[o] * rsqrtf(v1[o] + kEPS);
  float sh = b1[o] - m1[o] * s;
  float Pp = T[(size_t)bn * 512 + 256 + o];
  const int* ix = idx + (size_t)bn * KNBR;
  float mx = -3.0e38f;
#pragma unroll
  for (int k = 0; k < KNBR; k++) {
    int m = ix[k];
    float gg = T[((size_t)b * NN + m) * 512 + o];
    float y = (gg + Pp) * s + sh;
    y = y < 0.f ? 0.2f * y : y;
    mx = fmaxf(mx, y);
  }
  pooledb[(size_t)bn * 256 + o] = f2b(mx);
}

extern "C" void kernel_launch(void* const* d_in, const int* in_sizes, int n_in,
                              void* d_out, int out_size, void* d_ws,
                              size_t ws_size, hipStream_t stream) {
  const float* x = (const float*)d_in[0];
  const float* pos = (const float*)d_in[1];
  const float* w1 = (const float*)d_in[2];
  const float* gamma1 = (const float*)d_in[3];
  const float* beta1 = (const float*)d_in[4];
  const float* mean1 = (const float*)d_in[5];
  const float* var1 = (const float*)d_in[6];
  const float* w2 = (const float*)d_in[7];
  const float* gamma2 = (const float*)d_in[8];
  const float* beta2 = (const float*)d_in[9];
  const float* mean2 = (const float*)d_in[10];
  const float* var2 = (const float*)d_in[11];
  float* out = (float*)d_out;

  // ws layout (fp32 slots; total ~68.6 MB):
  float* ws = (float*)d_ws;
  float* s2 = ws;                                            // 768
  float* sh2 = s2 + 768;                                     // 768
  float* sqv = sh2 + 768;                                    // 16384
  unsigned short* w1b = (unsigned short*)(sqv + 16384);      // 512*768 u16
  unsigned short* w2b = w1b + 512 * 768;                     // 768*256 u16
  int* idx = (int*)(w2b + 768 * 256);                        // 65536 int
  unsigned short* hb = (unsigned short*)(idx + 65536);       // 4*4096*768 u16
  unsigned short* pooledb = hb + (size_t)BB * NN * CC;       // 4*4096*256 u16
  float* region = (float*)(pooledb + (size_t)BB * NN * 256); // 8.39M f shared
  unsigned short* dt = (unsigned short*)region;              // 4096*4096 bf16
  float* T = region;                                         // 16384*512 f32

  k_prep<<<BB * NN, 192, 0, stream>>>(x, pos, hb, sqv);
  k_wprep<<<2307, 256, 0, stream>>>(w1, w2, gamma2, beta2, mean2, var2,
                                    w1b, w2b, s2, sh2);
  for (int b = 0; b < BB; ++b) {
    const unsigned short* hbb = hb + (size_t)b * NN * CC;
    k_mm<0><<<1024, 256, 0, stream>>>(hbb, hbb, dt, sqv + (size_t)b * NN,
                                      nullptr, CC, NN, 32);
    k_topk<<<NN / 4, 256, 0, stream>>>(dt, x + (size_t)b * NN * CC,
                                       pos + (size_t)b * NN * CC,
                                       sqv + (size_t)b * NN,
                                       idx + (size_t)b * NN * KNBR);
  }
  k_mm<1><<<512, 256, 0, stream>>>(hb, w1b, T, nullptr, nullptr, CC, 512, 4);
  k_pool<<<BB * NN, 256, 0, stream>>>(T, idx, gamma1, beta1, mean1, var1, pooledb);
  k_mm<2><<<768, 256, 0, stream>>>(pooledb, w2b, out, s2, sh2, 256, CC, 6);
}

// Round 3
// 307.059 us; speedup vs baseline: 7.0594x; 1.6313x over previous
//
#include <hip/hip_runtime.h>

#define BB 4
#define NN 4096
#define CC 768
#define KNBR 4
constexpr float kEPS = 1e-5f;

typedef __attribute__((ext_vector_type(8))) short short8;
typedef __attribute__((ext_vector_type(4))) float f32x4;

__device__ __forceinline__ unsigned short f2b(float f) {  // fp32 -> bf16 RNE
  unsigned u = __float_as_uint(f);
  return (unsigned short)((u + 0x7fffu + ((u >> 16) & 1u)) >> 16);
}
__device__ __forceinline__ void gld16(const void* g, void* l) {
  __builtin_amdgcn_global_load_lds(
      (const __attribute__((address_space(1))) unsigned int*)g,
      (__attribute__((address_space(3))) unsigned int*)l, 16, 0, 0);
}

// ---------------- K1: hb = bf16(x + pos), sq[row] = sum(h^2) (fp32) --------
__global__ __launch_bounds__(192) void k_prep(const float* __restrict__ x,
                                              const float* __restrict__ pos,
                                              unsigned short* __restrict__ hb,
                                              float* __restrict__ sq) {
  int row = blockIdx.x;
  int t = threadIdx.x;
  const float4* x4 = reinterpret_cast<const float4*>(x + (size_t)row * CC);
  const float4* p4 = reinterpret_cast<const float4*>(pos + (size_t)row * CC);
  float4 a = x4[t], b = p4[t];
  float4 v;
  v.x = a.x + b.x; v.y = a.y + b.y; v.z = a.z + b.z; v.w = a.w + b.w;
  unsigned lo = (unsigned)f2b(v.x) | ((unsigned)f2b(v.y) << 16);
  unsigned hi = (unsigned)f2b(v.z) | ((unsigned)f2b(v.w) << 16);
  uint2 u; u.x = lo; u.y = hi;
  *reinterpret_cast<uint2*>(hb + (size_t)row * CC + t * 4) = u;
  float s = v.x * v.x + v.y * v.y + v.z * v.z + v.w * v.w;
  for (int off = 32; off > 0; off >>= 1) s += __shfl_down(s, off, 64);
  __shared__ float red[3];
  if ((t & 63) == 0) red[t >> 6] = s;
  __syncthreads();
  if (t == 0) sq[row] = red[0] + red[1] + red[2];
}

// ---------------- K2: weight prep: W1' (512x768 bf16), W2 bf16, BN2 affine --
__global__ __launch_bounds__(256) void k_wprep(const float* __restrict__ w1,
                                               const float* __restrict__ w2,
                                               const float* __restrict__ g2,
                                               const float* __restrict__ be2,
                                               const float* __restrict__ me2,
                                               const float* __restrict__ va2,
                                               unsigned short* __restrict__ w1b,
                                               unsigned short* __restrict__ w2b,
                                               float* __restrict__ s2,
                                               float* __restrict__ sh2) {
  int t = blockIdx.x * 256 + threadIdx.x;
  if (t < 512 * 768) {
    int o = t / 768, c = t % 768;
    float val = (o < 256) ? w1[(size_t)o * 1536 + c]
                          : (w1[(size_t)(o - 256) * 1536 + 768 + c] -
                             w1[(size_t)(o - 256) * 1536 + c]);
    w1b[t] = f2b(val);
  } else if (t < 512 * 768 + 768 * 256) {
    int u = t - 512 * 768;
    w2b[u] = f2b(w2[u]);
  } else if (t < 512 * 768 + 768 * 256 + 768) {
    int c = t - (512 * 768 + 768 * 256);
    float s = g2[c] * rsqrtf(va2[c] + kEPS);
    s2[c] = s;
    sh2[c] = be2[c] - me2[c] * s;
  }
}

// ---------------- K3: Gram MFMA + fused per-wave top-4 candidate epilogue --
// d~[i][j] = 2*G[i][j] - sq[j]  (row-constant shift of true d; order-preserving)
// cand[row][jt][wj][4] = packed (orderable-key[31:12] | j[11:0]) desc sorted.
__global__ __launch_bounds__(256) void k_gram(const unsigned short* __restrict__ hb,
                                              const float* __restrict__ sqv,
                                              unsigned* __restrict__ cand) {
  __shared__ unsigned short lds[16384];  // Qs [0..8191], Ps [8192..16383]
  const int tid = threadIdx.x, lane = tid & 63, w = tid >> 6;
  const int wi = w >> 1, wj = w & 1;
  int nwg = gridDim.x, bid = blockIdx.x;
  int wg = (bid & 7) * (nwg >> 3) + (bid >> 3);  // XCD swizzle (4096%8==0)
  int b = wg >> 10;
  int t = wg & 1023;
  int it = t >> 5, jt = t & 31;
  const unsigned short* H = hb + (size_t)b * NN * CC;
  const float* sqb = sqv + (size_t)b * NN;
  unsigned* cb = cand + (size_t)b * NN * 256;
  const size_t i0 = (size_t)it * 128, j0 = (size_t)jt * 128;

  const int srow = lane >> 3;
  const int chp = lane & 7;
  const int lc = chp ^ srow;

  f32x4 acc[4][4];
#pragma unroll
  for (int fi = 0; fi < 4; ++fi)
#pragma unroll
    for (int fj = 0; fj < 4; ++fj) acc[fi][fj] = (f32x4){0.f, 0.f, 0.f, 0.f};

  for (int k0 = 0; k0 < CC; k0 += 64) {
    __syncthreads();
#pragma unroll
    for (int p = 0; p < 4; ++p) {
      int row = p * 32 + w * 8 + srow;
      gld16(H + ((size_t)(j0 + row) * CC + k0 + lc * 8), &lds[row * 64 + chp * 8]);
    }
#pragma unroll
    for (int p = 0; p < 4; ++p) {
      int row = p * 32 + w * 8 + srow;
      gld16(H + ((size_t)(i0 + row) * CC + k0 + lc * 8),
            &lds[8192 + row * 64 + chp * 8]);
    }
    __syncthreads();
#pragma unroll
    for (int ks = 0; ks < 2; ++ks) {
      short8 qf[4], pf[4];
#pragma unroll
      for (int f = 0; f < 4; ++f) {
        int rq = wj * 64 + f * 16 + (lane & 15);
        int cq = (ks * 4 + (lane >> 4)) ^ (rq & 7);
        qf[f] = *(const short8*)&lds[rq * 64 + cq * 8];
        int rp = wi * 64 + f * 16 + (lane & 15);
        int cp = (ks * 4 + (lane >> 4)) ^ (rp & 7);
        pf[f] = *(const short8*)&lds[8192 + rp * 64 + cp * 8];
      }
#pragma unroll
      for (int fi = 0; fi < 4; ++fi)
#pragma unroll
        for (int fj = 0; fj < 4; ++fj)
          acc[fi][fj] = __builtin_amdgcn_mfma_f32_16x16x32_bf16(
              qf[fj], pf[fi], acc[fi][fj], 0, 0, 0);
    }
  }

  // fused epilogue: per (wave,row) top-4 over the wave's 64 j-values
  const int g = lane >> 4, l16 = lane & 15;
#pragma unroll
  for (int fi = 0; fi < 4; ++fi) {
    unsigned c0 = 0, c1 = 0, c2 = 0, c3 = 0;
#pragma unroll
    for (int fj = 0; fj < 4; ++fj) {
      int jl = (int)j0 + wj * 64 + fj * 16 + g * 4;
      float4 s4 = *(const float4*)&sqb[jl];
      float sa[4] = {s4.x, s4.y, s4.z, s4.w};
#pragma unroll
      for (int r = 0; r < 4; ++r) {
        float v = 2.f * acc[fi][fj][r] - sa[r];
        unsigned u = __float_as_uint(v);
        unsigned k = u ^ (unsigned)(((int)u >> 31) | 0x80000000);
        unsigned p = (k & 0xFFFFF000u) | (unsigned)(jl + r);
        if (p > c3) {
          c3 = p;
          unsigned tp;
          if (c3 > c2) { tp = c2; c2 = c3; c3 = tp; }
          if (c2 > c1) { tp = c1; c1 = c2; c2 = tp; }
          if (c1 > c0) { tp = c0; c0 = c1; c1 = tp; }
        }
      }
    }
#pragma unroll
    for (int off = 16; off <= 32; off <<= 1) {
      unsigned d0 = __shfl_xor((int)c0, off, 64);
      unsigned d1 = __shfl_xor((int)c1, off, 64);
      unsigned d2 = __shfl_xor((int)c2, off, 64);
      unsigned d3 = __shfl_xor((int)c3, off, 64);
      unsigned m0 = c0 > d3 ? c0 : d3;
      unsigned m1 = c1 > d2 ? c1 : d2;
      unsigned m2 = c2 > d1 ? c2 : d1;
      unsigned m3 = c3 > d0 ? c3 : d0;
      unsigned hi, lo;
      hi = m0 > m2 ? m0 : m2; lo = m0 > m2 ? m2 : m0; m0 = hi; m2 = lo;
      hi = m1 > m3 ? m1 : m3; lo = m1 > m3 ? m3 : m1; m1 = hi; m3 = lo;
      hi = m0 > m1 ? m0 : m1; lo = m0 > m1 ? m1 : m0; m0 = hi; m1 = lo;
      hi = m2 > m3 ? m2 : m3; lo = m2 > m3 ? m3 : m2; m2 = hi; m3 = lo;
      c0 = m0; c1 = m1; c2 = m2; c3 = m3;
    }
    if (g == fi) {
      size_t row = i0 + wi * 64 + fi * 16 + l16;
      uint4 o; o.x = c0; o.y = c1; o.z = c2; o.w = c3;
      *(uint4*)&cb[((row * 32 + jt) * 2 + wj) * 4] = o;
    }
  }
}

// ---------------- K4: bf16 MFMA GEMM (MLP layers) --------------------------
// MODE 1: raw fp32 out.  MODE 2: BN2 + leaky-relu fp32 out (e0=s2, e1=sh2)
template <int MODE>
__global__ __launch_bounds__(256) void k_mm(const unsigned short* __restrict__ P,
                                            const unsigned short* __restrict__ Q,
                                            void* __restrict__ outp,
                                            const float* __restrict__ e0,
                                            const float* __restrict__ e1,
                                            int K, int N, int jtiles) {
  __shared__ unsigned short lds[16384];
  const int tid = threadIdx.x, lane = tid & 63, w = tid >> 6;
  const int wi = w >> 1, wj = w & 1;
  int nwg = gridDim.x, bid = blockIdx.x;
  int wg = (bid & 7) * (nwg >> 3) + (bid >> 3);
  int it = wg / jtiles, jt = wg % jtiles;
  const size_t i0 = (size_t)it * 128, j0 = (size_t)jt * 128;

  const int srow = lane >> 3;
  const int chp = lane & 7;
  const int lc = chp ^ srow;

  f32x4 acc[4][4];
#pragma unroll
  for (int fi = 0; fi < 4; ++fi)
#pragma unroll
    for (int fj = 0; fj < 4; ++fj) acc[fi][fj] = (f32x4){0.f, 0.f, 0.f, 0.f};

  for (int k0 = 0; k0 < K; k0 += 64) {
    __syncthreads();
#pragma unroll
    for (int p = 0; p < 4; ++p) {
      int row = p * 32 + w * 8 + srow;
      gld16(Q + ((size_t)(j0 + row) * K + k0 + lc * 8), &lds[row * 64 + chp * 8]);
    }
#pragma unroll
    for (int p = 0; p < 4; ++p) {
      int row = p * 32 + w * 8 + srow;
      gld16(P + ((size_t)(i0 + row) * K + k0 + lc * 8),
            &lds[8192 + row * 64 + chp * 8]);
    }
    __syncthreads();
#pragma unroll
    for (int ks = 0; ks < 2; ++ks) {
      short8 qf[4], pf[4];
#pragma unroll
      for (int f = 0; f < 4; ++f) {
        int rq = wj * 64 + f * 16 + (lane & 15);
        int cq = (ks * 4 + (lane >> 4)) ^ (rq & 7);
        qf[f] = *(const short8*)&lds[rq * 64 + cq * 8];
        int rp = wi * 64 + f * 16 + (lane & 15);
        int cp = (ks * 4 + (lane >> 4)) ^ (rp & 7);
        pf[f] = *(const short8*)&lds[8192 + rp * 64 + cp * 8];
      }
#pragma unroll
      for (int fi = 0; fi < 4; ++fi)
#pragma unroll
        for (int fj = 0; fj < 4; ++fj)
          acc[fi][fj] = __builtin_amdgcn_mfma_f32_16x16x32_bf16(
              qf[fj], pf[fi], acc[fi][fj], 0, 0, 0);
    }
  }

#pragma unroll
  for (int fi = 0; fi < 4; ++fi) {
    size_t ig = i0 + wi * 64 + fi * 16 + (lane & 15);
#pragma unroll
    for (int fj = 0; fj < 4; ++fj) {
      size_t jg = j0 + wj * 64 + fj * 16 + ((lane >> 4) << 2);
      if (MODE == 1) {
        *(f32x4*)((float*)outp + ig * (size_t)N + jg) = acc[fi][fj];
      } else {
        f32x4 o4;
#pragma unroll
        for (int r = 0; r < 4; ++r) {
          size_t j = jg + r;
          float vv = acc[fi][fj][r] * e0[j] + e1[j];
          o4[r] = vv < 0.f ? 0.2f * vv : vv;
        }
        *(f32x4*)((float*)outp + ig * (size_t)N + jg) = o4;
      }
    }
  }
}

// ---------------- K5: top-12 of 256 packed candidates + exact fp32 rescue --
__global__ __launch_bounds__(256) void k_topk(const unsigned* __restrict__ cand,
                                              const float* __restrict__ x,
                                              const float* __restrict__ pos,
                                              const float* __restrict__ sqv,
                                              int* __restrict__ idxb) {
  const int w = threadIdx.x >> 6, lane = threadIdx.x & 63;
  const int gn = blockIdx.x * 4 + w;
  const int b = gn >> 12, n = gn & 4095;
  const float* xb = x + (size_t)b * NN * CC;
  const float* pb = pos + (size_t)b * NN * CC;
  const float* sqb = sqv + (size_t)b * NN;
  const unsigned* crow = cand + ((size_t)b * NN + n) * 256;

  uint4 q = *(const uint4*)(crow + lane * 4);
  unsigned c0 = q.x, c1 = q.y, c2 = q.z, c3 = q.w;  // already desc per group

  int cands[12];
#pragma unroll
  for (int r = 0; r < 12; ++r) {
    unsigned best = c0;
#pragma unroll
    for (int off = 1; off < 64; off <<= 1) {
      unsigned o = (unsigned)__shfl_xor((int)best, off, 64);
      best = o > best ? o : best;
    }
    cands[r] = (int)(best & 0xFFFu);
    if (c0 == best) { c0 = c1; c1 = c2; c2 = c3; c3 = 0; }
  }

  // Exact fp32 rescue: h = x + pos recomputed; 12 candidate dots; top-4.
  float hn[12];
  {
    const float4* xa = (const float4*)(xb + (size_t)n * CC + lane * 12);
    const float4* pa = (const float4*)(pb + (size_t)n * CC + lane * 12);
#pragma unroll
    for (int t = 0; t < 3; ++t) {
      float4 a = xa[t], bb = pa[t];
      hn[t * 4 + 0] = a.x + bb.x; hn[t * 4 + 1] = a.y + bb.y;
      hn[t * 4 + 2] = a.z + bb.z; hn[t * 4 + 3] = a.w + bb.w;
    }
  }
  float sqn = sqb[n];
  float b4v[4]; int b4m[4];
#pragma unroll
  for (int t = 0; t < 4; ++t) { b4v[t] = -3.0e38f; b4m[t] = 0x7fffffff; }

#pragma unroll
  for (int c = 0; c < 12; ++c) {
    int m = cands[c];
    const float4* xm = (const float4*)(xb + (size_t)m * CC + lane * 12);
    const float4* pm = (const float4*)(pb + (size_t)m * CC + lane * 12);
    float d = 0.f;
#pragma unroll
    for (int t = 0; t < 3; ++t) {
      float4 a = xm[t], bb = pm[t];
      d = fmaf(hn[t * 4 + 0], a.x + bb.x, d);
      d = fmaf(hn[t * 4 + 1], a.y + bb.y, d);
      d = fmaf(hn[t * 4 + 2], a.z + bb.z, d);
      d = fmaf(hn[t * 4 + 3], a.w + bb.w, d);
    }
#pragma unroll
    for (int off = 1; off < 64; off <<= 1) d += __shfl_xor(d, off, 64);
    float val = (2.f * d - sqn) - sqb[m];
    if (val > b4v[3] || (val == b4v[3] && m < b4m[3])) {
      b4v[3] = val; b4m[3] = m;
#pragma unroll
      for (int t = 3; t > 0; --t)
        if (b4v[t] > b4v[t - 1] || (b4v[t] == b4v[t - 1] && b4m[t] < b4m[t - 1])) {
          float tv = b4v[t]; b4v[t] = b4v[t - 1]; b4v[t - 1] = tv;
          int tm = b4m[t]; b4m[t] = b4m[t - 1]; b4m[t - 1] = tm;
        }
    }
  }
  if (lane == 0) {
    int4 o; o.x = b4m[0]; o.y = b4m[1]; o.z = b4m[2]; o.w = b4m[3];
    *(int4*)(idxb + (size_t)gn * KNBR) = o;
  }
}

// ---------------- K6: gather + BN1 + LReLU + max over K --------------------
__global__ __launch_bounds__(256) void k_pool(const float* __restrict__ T,
                                              const int* __restrict__ idx,
                                              const float* __restrict__ g1,
                                              const float* __restrict__ b1,
                                              const float* __restrict__ m1,
                                              const float* __restrict__ v1,
                                              unsigned short* __restrict__ pooledb) {
  int bn = blockIdx.x;
  int b = bn >> 12;
  int o = threadIdx.x;
  float s = g1[o] * rsqrtf(v1[o] + kEPS);
  float sh = b1[o] - m1[o] * s;
  float Pp = T[(size_t)bn * 512 + 256 + o];
  const int* ix = idx + (size_t)bn * KNBR;
  float mx = -3.0e38f;
#pragma unroll
  for (int k = 0; k < KNBR; k++) {
    int m = ix[k];
    float gg = T[((size_t)b * NN + m) * 512 + o];
    float y = (gg + Pp) * s + sh;
    y = y < 0.f ? 0.2f * y : y;
    mx = fmaxf(mx, y);
  }
  pooledb[(size_t)bn * 256 + o] = f2b(mx);
}

extern "C" void kernel_launch(void* const* d_in, const int* in_sizes, int n_in,
                              void* d_out, int out_size, void* d_ws,
                              size_t ws_size, hipStream_t stream) {
  const float* x = (const float*)d_in[0];
  const float* pos = (const float*)d_in[1];
  const float* w1 = (const float*)d_in[2];
  const float* gamma1 = (const float*)d_in[3];
  const float* beta1 = (const float*)d_in[4];
  const float* mean1 = (const float*)d_in[5];
  const float* var1 = (const float*)d_in[6];
  const float* w2 = (const float*)d_in[7];
  const float* gamma2 = (const float*)d_in[8];
  const float* beta2 = (const float*)d_in[9];
  const float* mean2 = (const float*)d_in[10];
  const float* var2 = (const float*)d_in[11];
  float* out = (float*)d_out;

  // ws layout (~70 MB): cand aliases T (disjoint live ranges, stream-ordered)
  float* ws = (float*)d_ws;
  float* s2 = ws;                                            // 768
  float* sh2 = s2 + 768;                                     // 768
  float* sqv = sh2 + 768;                                    // 16384
  unsigned short* w1b = (unsigned short*)(sqv + 16384);      // 512*768 u16
  unsigned short* w2b = w1b + 512 * 768;                     // 768*256 u16
  int* idx = (int*)(w2b + 768 * 256);                        // 65536 int
  unsigned short* hb = (unsigned short*)(idx + 65536);       // 4*4096*768 u16
  unsigned short* pooledb = hb + (size_t)BB * NN * CC;       // 4*4096*256 u16
  float* region = (float*)(pooledb + (size_t)BB * NN * 256); // 33.5MB shared
  unsigned* cand = (unsigned*)region;                        // 4*4096*256 u32
  float* T = region;                                         // 16384*512 f32

  k_prep<<<BB * NN, 192, 0, stream>>>(x, pos, hb, sqv);
  k_wprep<<<2307, 256, 0, stream>>>(w1, w2, gamma2, beta2, mean2, var2,
                                    w1b, w2b, s2, sh2);
  k_gram<<<BB * 1024, 256, 0, stream>>>(hb, sqv, cand);
  k_topk<<<BB * NN / 4, 256, 0, stream>>>(cand, x, pos, sqv, idx);
  k_mm<1><<<512, 256, 0, stream>>>(hb, w1b, T, nullptr, nullptr, CC, 512, 4);
  k_pool<<<BB * NN, 256, 0, stream>>>(T, idx, gamma1, beta1, mean1, var1, pooledb);
  k_mm<2><<<768, 256, 0, stream>>>(pooledb, w2b, out, s2, sh2, 256, CC, 6);
}